// Round 3
// baseline (58.796 us; speedup 1.0000x reference)
//
#include <hip/hip_runtime.h>

// Problem constants (match reference setup_inputs)
#define NBAGS 64
#define D 512            // feature dim (floats)
#define D4 128           // feature dim in float4
#define RPC 128          // rows per chunk (equal-work unit)
#define TTOT 131072      // total rows
#define MAXCHUNKS (TTOT / RPC + NBAGS)   // 1088 upper bound on total chunks

// Pass 1: one block per (bag-proportional) chunk of <=RPC rows.
// grid = MAXCHUNKS, block = 256. Thread t: float4 col (t&127), row parity (t>>7).
__global__ void agg_partial_kernel(const float* __restrict__ samples,
                                   const int* __restrict__ counts,
                                   float* __restrict__ partials) {
    const int g = blockIdx.x;   // global chunk id

    // Identical scan in both kernels: per-bag chunk counts + prefixes.
    int bag = -1, mychunk = 0;
    long long rowbase = 0, cnt = 0;
    {
        long long cb = 0, rb = 0;
#pragma unroll
        for (int i = 0; i < NBAGS; ++i) {
            long long c  = (long long)counts[i];
            int       nc = (int)((c + RPC - 1) / RPC);
            if (bag < 0 && g >= cb && g < cb + nc) {
                bag = i; mychunk = (int)(g - cb); rowbase = rb; cnt = c;
            }
            cb += nc; rb += c;
        }
    }
    if (bag < 0) return;  // beyond total chunk count

    const long long r0 = rowbase + (long long)mychunk * RPC;
    const long long r1 = min(rowbase + cnt, r0 + (long long)RPC);

    const int t    = threadIdx.x;
    const int col  = t & (D4 - 1);
    const int half = t >> 7;

    const float4* __restrict__ src = (const float4*)samples;  // row stride D4

    float4 a0 = make_float4(0.f, 0.f, 0.f, 0.f);
    float4 a1 = make_float4(0.f, 0.f, 0.f, 0.f);
    long long r = r0 + half;
    // 4 loads in flight per thread (rows stride 2 within chunk).
    for (; r + 6 < r1; r += 8) {
        float4 v0 = src[(r    ) * D4 + col];
        float4 v1 = src[(r + 2) * D4 + col];
        float4 v2 = src[(r + 4) * D4 + col];
        float4 v3 = src[(r + 6) * D4 + col];
        a0.x += v0.x; a0.y += v0.y; a0.z += v0.z; a0.w += v0.w;
        a1.x += v1.x; a1.y += v1.y; a1.z += v1.z; a1.w += v1.w;
        a0.x += v2.x; a0.y += v2.y; a0.z += v2.z; a0.w += v2.w;
        a1.x += v3.x; a1.y += v3.y; a1.z += v3.z; a1.w += v3.w;
    }
    for (; r < r1; r += 2) {
        float4 v = src[r * D4 + col];
        a0.x += v.x; a0.y += v.y; a0.z += v.z; a0.w += v.w;
    }
    a0.x += a1.x; a0.y += a1.y; a0.z += a1.z; a0.w += a1.w;

    // Combine the two row-parity halves through LDS; half 0 writes out.
    __shared__ float4 lds[D4];
    if (half == 1) lds[col] = a0;
    __syncthreads();
    if (half == 0) {
        float4 o = lds[col];
        a0.x += o.x; a0.y += o.y; a0.z += o.z; a0.w += o.w;
        ((float4*)partials)[(long long)g * D4 + col] = a0;
    }
}

// Pass 2: one block per bag; reduce its ceil(cnt/RPC) chunk partials in fixed
// order, scale by 1/count, write out. grid = NBAGS, block = D4.
__global__ void agg_reduce_kernel(const float* __restrict__ partials,
                                  const int* __restrict__ counts,
                                  float* __restrict__ out) {
    const int bag = blockIdx.x;
    const int col = threadIdx.x;  // 0..D4-1

    // Same scan: chunk base + count for this bag.
    long long cb = 0; int nc = 0; long long cnt = 0;
#pragma unroll
    for (int i = 0; i < NBAGS; ++i) {
        long long c  = (long long)counts[i];
        int       n  = (int)((c + RPC - 1) / RPC);
        if (i == bag) { nc = n; cnt = c; break; }
        cb += n;
    }

    const float4* __restrict__ p = (const float4*)partials;
    float4 acc = make_float4(0.f, 0.f, 0.f, 0.f);
    for (int c = 0; c < nc; ++c) {
        float4 v = p[(cb + c) * D4 + col];
        acc.x += v.x; acc.y += v.y; acc.z += v.z; acc.w += v.w;
    }
    const float inv = 1.0f / (float)cnt;
    acc.x *= inv; acc.y *= inv; acc.z *= inv; acc.w *= inv;
    ((float4*)out)[bag * D4 + col] = acc;
}

extern "C" void kernel_launch(void* const* d_in, const int* in_sizes, int n_in,
                              void* d_out, int out_size, void* d_ws, size_t ws_size,
                              hipStream_t stream) {
    const float* samples  = (const float*)d_in[0];
    const int*   counts   = (const int*)d_in[1];   // harness converts int64 -> int32
    float*       out      = (float*)d_out;
    float*       partials = (float*)d_ws;          // MAXCHUNKS*D floats = 2.2 MiB

    agg_partial_kernel<<<MAXCHUNKS, 256, 0, stream>>>(samples, counts, partials);
    agg_reduce_kernel<<<NBAGS, D4, 0, stream>>>(partials, counts, out);
}